// Round 1
// baseline (172.002 us; speedup 1.0000x reference)
//
#include <hip/hip_runtime.h>

// TsSub: out[b, p, t] = x[b, I[p], t*10] - x[b, J[p], t*10]
// x: (256, 64, 2000) f32, out: (256, 2016, 200) f32
// (I, J) = triu_indices(64, k=1)

#define NF     64
#define T_IN   2000
#define T_OUT  200
#define NPAIR  2016     // 64*63/2
#define SSTRIDE 10
#define NB     256
#define NTHREADS 1024

__global__ __launch_bounds__(NTHREADS)
void ts_sub_kernel(const float* __restrict__ x, float* __restrict__ out) {
    // sampled[b] staged in LDS: 64 rows x 200 cols f32 = 51200 B
    __shared__ __attribute__((aligned(16))) float s[NF * T_OUT];
    __shared__ unsigned char pi[NPAIR];
    __shared__ unsigned char pj[NPAIR];

    const int b   = blockIdx.x;
    const int tid = threadIdx.x;
    const float* __restrict__ xb = x + (size_t)b * (NF * T_IN);

    // --- stage sampled[b] into LDS (reads each b's input lines exactly once) ---
    for (int idx = tid; idx < NF * T_OUT; idx += NTHREADS) {
        int f = idx / T_OUT;
        int t = idx - f * T_OUT;
        s[idx] = xb[f * T_IN + t * SSTRIDE];
    }

    // --- build triu pair table: find largest i with S(i) <= p, S(i) = i*(127-i)/2 ---
    for (int p = tid; p < NPAIR; p += NTHREADS) {
        float d = 16129.0f - 8.0f * (float)p;          // 127^2 - 8p
        int i = (int)((127.0f - sqrtf(d)) * 0.5f);
        if (i < 0) i = 0;
        while (i > 0 && (i * (127 - i)) / 2 > p) --i;          // S(i) > p -> too big
        while (((i + 1) * (126 - i)) / 2 <= p) ++i;            // S(i+1) <= p -> too small
        int j = p - (i * (127 - i)) / 2 + i + 1;
        pi[p] = (unsigned char)i;
        pj[p] = (unsigned char)j;
    }
    __syncthreads();

    // --- stream outputs as float4: 2016*200/4 = 100800 vec4 per b ---
    float* __restrict__ ob = out + (size_t)b * (NPAIR * T_OUT);
    const int NV = NPAIR * T_OUT / 4;   // 100800, T_OUT%4==0 so each vec4 is within one row
    for (int v = tid; v < NV; v += NTHREADS) {
        int p  = v / (T_OUT / 4);            // 50 vec4 per pair-row
        int t4 = v - p * (T_OUT / 4);
        int i = pi[p];
        int j = pj[p];
        const float4 a = *reinterpret_cast<const float4*>(&s[i * T_OUT + t4 * 4]);
        const float4 c = *reinterpret_cast<const float4*>(&s[j * T_OUT + t4 * 4]);
        float4 r;
        r.x = a.x - c.x;
        r.y = a.y - c.y;
        r.z = a.z - c.z;
        r.w = a.w - c.w;
        *reinterpret_cast<float4*>(&ob[(size_t)v * 4]) = r;
    }
}

extern "C" void kernel_launch(void* const* d_in, const int* in_sizes, int n_in,
                              void* d_out, int out_size, void* d_ws, size_t ws_size,
                              hipStream_t stream) {
    const float* x = (const float*)d_in[0];
    float* out = (float*)d_out;
    ts_sub_kernel<<<dim3(NB), dim3(NTHREADS), 0, stream>>>(x, out);
}

// Round 2
// 168.770 us; speedup vs baseline: 1.0192x; 1.0192x over previous
//
#include <hip/hip_runtime.h>

// TsSub: out[b, p, t] = x[b, I[p], t*10] - x[b, J[p], t*10]
// x: (256, 64, 2000) f32, out: (256, 2016, 200) f32
// (I, J) = triu_indices(64, k=1)
//
// Two-kernel plan:
//  K1: samp[b,f,t] = x[b,f,10t]  (13.1 MB into d_ws) - strided read, coalesced write
//  K2: out[b,p,t]  = samp[b,I[p],t] - samp[b,J[p],t] - L2-served reads, streaming write

#define NF      64
#define T_IN    2000
#define T_OUT   200
#define NPAIR   2016     // 64*63/2
#define SSTRIDE 10
#define NB      256
#define TV4     (T_OUT / 4)          // 50 vec4 per row
#define CHUNKS  8                    // output chunks per batch in K2
#define CV      (NPAIR * TV4 / CHUNKS)  // 12600 vec4 per chunk

// ---------------- K1: gather sampled into ws ----------------
__global__ __launch_bounds__(256)
void gather_kernel(const float* __restrict__ x, float* __restrict__ samp) {
    const int N = NB * NF * T_OUT;   // 3,276,800
    const int stride = gridDim.x * blockDim.x;
    for (int idx = blockIdx.x * blockDim.x + threadIdx.x; idx < N; idx += stride) {
        int row = idx / T_OUT;            // b*64 + f
        int t   = idx - row * T_OUT;
        samp[idx] = x[(size_t)row * T_IN + t * SSTRIDE];
    }
}

// ---------------- K2: pair subtraction ----------------
__global__ __launch_bounds__(256)
void pairsub_kernel(const float* __restrict__ samp, float* __restrict__ out) {
    __shared__ unsigned char pi[NPAIR];
    __shared__ unsigned char pj[NPAIR];

    // build triu pair table (tiny: 8 iters/thread)
    for (int p = threadIdx.x; p < NPAIR; p += 256) {
        float d = 16129.0f - 8.0f * (float)p;          // 127^2 - 8p
        int i = (int)((127.0f - sqrtf(d)) * 0.5f);
        if (i < 0) i = 0;
        while (i > 0 && (i * (127 - i)) / 2 > p) --i;
        while (((i + 1) * (126 - i)) / 2 <= p) ++i;
        pi[p] = (unsigned char)i;
        pj[p] = (unsigned char)(p - (i * (127 - i)) / 2 + i + 1);
    }
    __syncthreads();

    const int b     = blockIdx.x >> 3;        // blockIdx = b*8 + chunk
    const int chunk = blockIdx.x & 7;

    const float4* __restrict__ sb = reinterpret_cast<const float4*>(samp)
                                    + (size_t)b * (NF * TV4);
    float4* __restrict__ ob = reinterpret_cast<float4*>(out)
                              + (size_t)b * (NPAIR * TV4) + (size_t)chunk * CV;
    const int base = chunk * CV;

    for (int u = threadIdx.x; u < CV; u += 256) {
        int v  = base + u;
        int p  = v / TV4;                 // magic-mul div by 50
        int t4 = v - p * TV4;
        const float4 a = sb[pi[p] * TV4 + t4];
        const float4 c = sb[pj[p] * TV4 + t4];
        float4 r;
        r.x = a.x - c.x;
        r.y = a.y - c.y;
        r.z = a.z - c.z;
        r.w = a.w - c.w;
        ob[u] = r;
    }
}

extern "C" void kernel_launch(void* const* d_in, const int* in_sizes, int n_in,
                              void* d_out, int out_size, void* d_ws, size_t ws_size,
                              hipStream_t stream) {
    const float* x = (const float*)d_in[0];
    float* out = (float*)d_out;
    float* samp = (float*)d_ws;       // needs 13,107,200 B

    gather_kernel<<<dim3(2048), dim3(256), 0, stream>>>(x, samp);
    pairsub_kernel<<<dim3(NB * CHUNKS), dim3(256), 0, stream>>>(samp, out);
}

// Round 3
// 129.149 us; speedup vs baseline: 1.3318x; 1.3068x over previous
//
#include <hip/hip_runtime.h>

// TsSub: out[b, p, t] = x[b, I[p], t*10] - x[b, J[p], t*10]
// x: (256, 64, 2000) f32, out: (256, 2016, 200) f32, (I,J)=triu_indices(64,k=1)
//
//  K1: samp[b,f,t] = x[b,f,10t]  (13.1 MB into d_ws)
//  K2: feature-group-tiled pair-sub: block = (b, group-pair), 16-row groups
//      staged in LDS -> global reads ~60 MB instead of 826 MB.

#define NF      64
#define T_IN    2000
#define T_OUT   200
#define NPAIR   2016
#define SSTRIDE 10
#define NB      256
#define TV4     (T_OUT / 4)     // 50 float4 per row
#define LPAD    51              // padded LDS row stride in float4
#define NCOMBO  10              // 4 diag + 6 off-diag group pairs (G=16)

__constant__ unsigned char kGi[NCOMBO] = {0,1,2,3, 0,0,0,1,1,2};
__constant__ unsigned char kGj[NCOMBO] = {0,1,2,3, 1,2,3,2,3,3};

// ---------------- K1: gather sampled into ws ----------------
__global__ __launch_bounds__(256)
void gather_kernel(const float* __restrict__ x, float* __restrict__ samp) {
    const int N = NB * NF * T_OUT;   // 3,276,800
    const int stride = gridDim.x * blockDim.x;
    for (int idx = blockIdx.x * blockDim.x + threadIdx.x; idx < N; idx += stride) {
        int row = idx / T_OUT;            // b*64 + f
        int t   = idx - row * T_OUT;
        samp[idx] = x[(size_t)row * T_IN + t * SSTRIDE];
    }
}

// ---------------- K2: tiled pair subtraction ----------------
__global__ __launch_bounds__(256)
void pairsub_tiled(const float4* __restrict__ samp, float4* __restrict__ out) {
    __shared__ __attribute__((aligned(16))) float4 s[32 * LPAD];  // 26.1 KB
    __shared__ int obase[256];
    __shared__ unsigned char ir[256];
    __shared__ unsigned char jr[256];

    const int tid   = threadIdx.x;
    const int blk   = blockIdx.x;
    const int b     = blk / NCOMBO;
    const int combo = blk - b * NCOMBO;
    const int gi    = kGi[combo];
    const int gj    = kGj[combo];
    const bool diag = combo < 4;
    const int nrows  = diag ? 16 : 32;
    const int npairs = diag ? 120 : 256;

    // --- pair tables ---
    if (tid < npairs) {
        int il, jl;
        if (diag) {
            il = 0;                                   // base16(i) = i*(31-i)/2
            while ((il + 1) * (30 - il) / 2 <= tid) ++il;
            jl = tid - il * (31 - il) / 2 + il + 1;
            ir[tid] = (unsigned char)il;
            jr[tid] = (unsigned char)jl;              // same group: slots 0..15
        } else {
            il = tid >> 4; jl = tid & 15;
            ir[tid] = (unsigned char)il;
            jr[tid] = (unsigned char)(16 + jl);
        }
        int i = gi * 16 + il;
        int j = (diag ? gi : gj) * 16 + jl;
        obase[tid] = i * (127 - i) / 2 + (j - i - 1);
    }

    // --- stage rows into LDS ---
    const float4* __restrict__ sb = samp + (size_t)b * (NF * TV4);
    for (int idx = tid; idx < nrows * TV4; idx += 256) {
        int slot = idx / TV4;
        int t4   = idx - slot * TV4;
        int f    = (slot < 16) ? (gi * 16 + slot) : (gj * 16 + slot - 16);
        s[slot * LPAD + t4] = sb[f * TV4 + t4];
    }
    __syncthreads();

    // --- emit pair rows ---
    float4* __restrict__ ob = out + (size_t)b * (NPAIR * TV4);
    const int total = npairs * TV4;          // 12800 or 6000
    for (int v = tid; v < total; v += 256) {
        int slot = v / TV4;
        int t4   = v - slot * TV4;
        float4 a = s[ir[slot] * LPAD + t4];
        float4 c = s[jr[slot] * LPAD + t4];
        float4 r;
        r.x = a.x - c.x;
        r.y = a.y - c.y;
        r.z = a.z - c.z;
        r.w = a.w - c.w;
        ob[(size_t)obase[slot] * TV4 + t4] = r;
    }
}

extern "C" void kernel_launch(void* const* d_in, const int* in_sizes, int n_in,
                              void* d_out, int out_size, void* d_ws, size_t ws_size,
                              hipStream_t stream) {
    const float* x = (const float*)d_in[0];
    float* out = (float*)d_out;
    float* samp = (float*)d_ws;       // 13,107,200 B

    gather_kernel<<<dim3(2048), dim3(256), 0, stream>>>(x, samp);
    pairsub_tiled<<<dim3(NB * NCOMBO), dim3(256), 0, stream>>>(
        (const float4*)samp, (float4*)out);
}

// Round 4
// 126.168 us; speedup vs baseline: 1.3633x; 1.0236x over previous
//
#include <hip/hip_runtime.h>

// TsSub: out[b, p, t] = x[b, I[p], t*10] - x[b, J[p], t*10]
// x: (256, 64, 2000) f32, out: (256, 2016, 200) f32, (I,J)=triu_indices(64,k=1)
//
//  K1: line-staged gather: block streams 2 full x-rows into LDS (coalesced
//      float4), emits sampled rows into d_ws.  131 MB read + 13 MB write.
//  K2: feature-group-tiled pair-sub (G=16, 10 combos/b), XCD-chunk swizzled
//      so same-b combos share one XCD's L2; incremental (slot,t4) indexing.

#define NF      64
#define T_IN    2000
#define T_OUT   200
#define NPAIR   2016
#define NB      256
#define TV4     (T_OUT / 4)     // 50 float4 per row
#define LPAD    51              // padded LDS row stride in float4
#define NCOMBO  10              // 4 diag + 6 off-diag group pairs (G=16)
#define K2_NWG  (NB * NCOMBO)   // 2560
#define RPB     2               // x-rows per K1 block
#define RV4     (T_IN / 4)      // 500 float4 per x-row

__constant__ unsigned char kGi[NCOMBO] = {0,1,2,3, 0,0,0,1,1,2};
__constant__ unsigned char kGj[NCOMBO] = {0,1,2,3, 1,2,3,2,3,3};

// ---------------- K1: line-staged gather ----------------
__global__ __launch_bounds__(256)
void gather_kernel(const float4* __restrict__ xv, float* __restrict__ samp) {
    __shared__ __attribute__((aligned(16))) float4 ls[RPB * RV4];   // 16 KB
    const int blk = blockIdx.x;     // 16384/RPB = 8192 blocks
    const float4* __restrict__ src = xv + (size_t)blk * (RPB * RV4);
    for (int i = threadIdx.x; i < RPB * RV4; i += 256) ls[i] = src[i];
    __syncthreads();
    const float* lf = (const float*)ls;
    float4* __restrict__ dst =
        reinterpret_cast<float4*>(samp + (size_t)blk * (RPB * T_OUT));
    for (int q = threadIdx.x; q < RPB * TV4; q += 256) {   // 100 float4
        int lr = q / TV4;
        int t4 = q - lr * TV4;
        int base = lr * T_IN + t4 * 40;
        float4 r;
        r.x = lf[base];
        r.y = lf[base + 10];
        r.z = lf[base + 20];
        r.w = lf[base + 30];
        dst[q] = r;
    }
}

// ---------------- K2: tiled pair subtraction ----------------
__global__ __launch_bounds__(256)
void pairsub_tiled(const float4* __restrict__ samp, float4* __restrict__ out) {
    __shared__ __attribute__((aligned(16))) float4 s[32 * LPAD];  // 26.1 KB
    __shared__ int obase[256];
    __shared__ unsigned char ir[256];
    __shared__ unsigned char jr[256];

    const int tid = threadIdx.x;
    // bijective XCD-chunk swizzle: HW dispatches n round-robin over 8 XCDs;
    // remap so logical blocks 0..319 (b=0..31, all combos) share XCD 0, etc.
    const int n   = blockIdx.x;
    const int blk = (n & 7) * (K2_NWG / 8) + (n >> 3);
    const int b     = blk / NCOMBO;
    const int combo = blk - b * NCOMBO;
    const int gi    = kGi[combo];
    const int gj    = kGj[combo];
    const bool diag = combo < 4;
    const int nrows  = diag ? 16 : 32;
    const int npairs = diag ? 120 : 256;

    // --- pair tables ---
    if (tid < npairs) {
        int il, jl;
        if (diag) {
            il = 0;                                   // base16(i) = i*(31-i)/2
            while ((il + 1) * (30 - il) / 2 <= tid) ++il;
            jl = tid - il * (31 - il) / 2 + il + 1;
            ir[tid] = (unsigned char)il;
            jr[tid] = (unsigned char)jl;
        } else {
            il = tid >> 4; jl = tid & 15;
            ir[tid] = (unsigned char)il;
            jr[tid] = (unsigned char)(16 + jl);
        }
        int i = gi * 16 + il;
        int j = (diag ? gi : gj) * 16 + jl;
        obase[tid] = i * (127 - i) / 2 + (j - i - 1);
    }

    // --- stage rows into LDS ---
    const float4* __restrict__ sb = samp + (size_t)b * (NF * TV4);
    for (int idx = tid; idx < nrows * TV4; idx += 256) {
        int slot = idx / TV4;
        int t4   = idx - slot * TV4;
        int f    = (slot < 16) ? (gi * 16 + slot) : (gj * 16 + slot - 16);
        s[slot * LPAD + t4] = sb[f * TV4 + t4];
    }
    __syncthreads();

    // --- emit pair rows: incremental (slot,t4), step 256 = 5*50 + 6 ---
    float4* __restrict__ ob = out + (size_t)b * (NPAIR * TV4);
    const int total = npairs * TV4;          // 12800 or 6000
    int v    = tid;
    int slot = v / TV4;
    int t4   = v - slot * TV4;
    while (v < total) {
        float4 a = s[ir[slot] * LPAD + t4];
        float4 c = s[jr[slot] * LPAD + t4];
        float4 r;
        r.x = a.x - c.x;
        r.y = a.y - c.y;
        r.z = a.z - c.z;
        r.w = a.w - c.w;
        ob[(size_t)obase[slot] * TV4 + t4] = r;
        v += 256;
        slot += 5;
        t4 += 6;
        if (t4 >= TV4) { t4 -= TV4; ++slot; }
    }
}

extern "C" void kernel_launch(void* const* d_in, const int* in_sizes, int n_in,
                              void* d_out, int out_size, void* d_ws, size_t ws_size,
                              hipStream_t stream) {
    const float* x = (const float*)d_in[0];
    float* out = (float*)d_out;
    float* samp = (float*)d_ws;       // 13,107,200 B

    gather_kernel<<<dim3(NB * NF / RPB), dim3(256), 0, stream>>>(
        (const float4*)x, samp);
    pairsub_tiled<<<dim3(K2_NWG), dim3(256), 0, stream>>>(
        (const float4*)samp, (float4*)out);
}